// Round 6
// baseline (446.606 us; speedup 1.0000x reference)
//
#include <hip/hip_runtime.h>
#include <hip/hip_bf16.h>
#include <hip/hip_fp16.h>

#define Bn 8
#define Tn 4096
#define En 2048
#define Hn 128

typedef __attribute__((ext_vector_type(8))) short bf16x8;
typedef __attribute__((ext_vector_type(4))) float f32x4;
typedef __attribute__((ext_vector_type(4))) unsigned int u32x4;

typedef const __attribute__((address_space(1))) unsigned int* gptr_t;
typedef __attribute__((address_space(3))) unsigned int* lptr_t;

static __device__ __forceinline__ void gload16(const void* g, void* l) {
    __builtin_amdgcn_global_load_lds((gptr_t)g, (lptr_t)l, 16, 0, 0);
}

static __device__ __forceinline__ unsigned short f2bf(float f) {
    union { float f; unsigned u; } v; v.f = f;
    unsigned r = v.u + 0x7FFFu + ((v.u >> 16) & 1u);
    return (unsigned short)(r >> 16);
}
static __device__ __forceinline__ short bfbits(float f) {
    __hip_bfloat16 h = __float2bfloat16(f);
    return *reinterpret_cast<short*>(&h);
}
static __device__ __forceinline__ float h2f(unsigned short bits) {
    __half_raw hr; hr.x = bits;
    return __half2float(__half(hr));
}

// P-fragment: 8 fp16 scores -> exp2(s - mr) -> bf16x8 (A-operand, in-register)
static __device__ __forceinline__ bf16x8 expfrag(u32x4 raw, const float* mk) {
    bf16x8 o;
    #pragma unroll
    for (int i = 0; i < 4; ++i) {
        float f0 = h2f((unsigned short)(raw[i] & 0xffff));
        float f1 = h2f((unsigned short)(raw[i] >> 16));
        o[2 * i]     = bfbits(__builtin_amdgcn_exp2f(f0 - mk[2 * i]));
        o[2 * i + 1] = bfbits(__builtin_amdgcn_exp2f(f1 - mk[2 * i + 1]));
    }
    return o;
}

// ---------------- K-1: x fp32 -> bf16, one streaming pass --------------------
__global__ __launch_bounds__(256) void conv_x(const float* __restrict__ x,
                                              unsigned short* __restrict__ xb) {
    size_t i = ((size_t)blockIdx.x * 256 + threadIdx.x) * 8;
    float4 a = *reinterpret_cast<const float4*>(x + i);
    float4 b = *reinterpret_cast<const float4*>(x + i + 4);
    ushort4 o0, o1;
    o0.x = f2bf(a.x); o0.y = f2bf(a.y); o0.z = f2bf(a.z); o0.w = f2bf(a.w);
    o1.x = f2bf(b.x); o1.y = f2bf(b.y); o1.z = f2bf(b.z); o1.w = f2bf(b.w);
    *reinterpret_cast<ushort4*>(xb + i) = o0;
    *reinterpret_cast<ushort4*>(xb + i + 4) = o1;
}

// ---------------- K0: transpose+convert weights, fold SCALE*log2e into Wq ----
__global__ __launch_bounds__(256) void prep_w(const float* __restrict__ Wq,
                                              const float* __restrict__ Wk,
                                              const float* __restrict__ Wv,
                                              unsigned short* __restrict__ Wt) {
    int idx = blockIdx.x * 256 + threadIdx.x;          // over 3*E*H, input-coalesced
    int w = idx / (En * Hn);
    int rem = idx - w * (En * Hn);
    int kx = rem >> 7;                                  // k (0..2047)
    int n  = rem & 127;                                 // h (0..127)
    const float* W = (w == 0) ? Wq : (w == 1) ? Wk : Wv;
    float f = W[rem];
    if (w == 0) f *= (0.17677669529663687f * 1.4426950408889634f); // 32^-0.5 * log2(e)
    Wt[(size_t)w * En * Hn + (size_t)n * En + kx] = f2bf(f);
}

// ---------------- K1: qkv projection — m97 structure, pure bf16 --------------
__global__ __launch_bounds__(256, 3) void qkv_mfma(const unsigned short* __restrict__ xb,
                                                   const unsigned short* __restrict__ Wt,
                                                   unsigned short* __restrict__ qs,
                                                   unsigned short* __restrict__ ks,
                                                   unsigned short* __restrict__ vT) {
    __shared__ unsigned short Al[128][64];  // 16 KB, rows 128 B, linear
    __shared__ unsigned short Bl[128][64];  // 16 KB
    const int bid = blockIdx.x;
    const int w = bid % 3;
    const int m0 = (bid / 3) * 128;
    const int b = m0 >> 12;
    const int tb = m0 & (Tn - 1);
    const int t = threadIdx.x;
    const int lane = t & 63, wid = t >> 6;
    const int wr = (wid >> 1) * 64, wc = (wid & 1) * 64;
    const int fr = lane & 15, fq = lane >> 4;
    const unsigned short* Wb = Wt + (size_t)w * En * Hn;
    const int sr = lane >> 3, sc = lane & 7;

    f32x4 acc[4][4] = {};
    for (int k0 = 0; k0 < En; k0 += 64) {
        __syncthreads();
        #pragma unroll
        for (int s = 0; s < 4; ++s) {
            int seg = wid * 4 + s;
            int r = seg * 8 + sr;
            gload16(&xb[(size_t)(m0 + r) * En + k0 + sc * 8],
                    (char*)&Al[0][0] + seg * 1024 + lane * 16);
            gload16(&Wb[(size_t)r * En + k0 + sc * 8],
                    (char*)&Bl[0][0] + seg * 1024 + lane * 16);
        }
        __syncthreads();
        #pragma unroll
        for (int ksub = 0; ksub < 2; ++ksub) {
            bf16x8 av[4], bv[4];
            #pragma unroll
            for (int mi = 0; mi < 4; ++mi)
                av[mi] = *reinterpret_cast<const bf16x8*>(&Al[wr + mi * 16 + fr][ksub * 32 + fq * 8]);
            #pragma unroll
            for (int ni = 0; ni < 4; ++ni)
                bv[ni] = *reinterpret_cast<const bf16x8*>(&Bl[wc + ni * 16 + fr][ksub * 32 + fq * 8]);
            #pragma unroll
            for (int mi = 0; mi < 4; ++mi)
                #pragma unroll
                for (int ni = 0; ni < 4; ++ni)
                    acc[mi][ni] = __builtin_amdgcn_mfma_f32_16x16x32_bf16(av[mi], bv[ni], acc[mi][ni], 0, 0, 0);
        }
    }

    if (w < 2) {
        unsigned short* out = (w == 0) ? qs : ks;
        #pragma unroll
        for (int mi = 0; mi < 4; ++mi)
            #pragma unroll
            for (int ni = 0; ni < 4; ++ni)
                #pragma unroll
                for (int r = 0; r < 4; ++r) {
                    int row = m0 + wr + mi * 16 + fq * 4 + r;
                    int col = wc + ni * 16 + fr;
                    out[(size_t)row * Hn + col] = f2bf(acc[mi][ni][r]);
                }
    } else {
        #pragma unroll
        for (int mi = 0; mi < 4; ++mi)
            #pragma unroll
            for (int ni = 0; ni < 4; ++ni)
                #pragma unroll
                for (int r = 0; r < 4; ++r) {
                    int tt = tb + wr + mi * 16 + fq * 4 + r;
                    int h  = wc + ni * 16 + fr;
                    vT[((size_t)b * Hn + h) * Tn + tt] = f2bf(acc[mi][ni][r]);
                }
    }
}

// ---------------- K2: S' = q'.k^T -> fp16 [b][q][k]  +  fused column stats ---
// Epilogue restaged through LDS (aliases Ql/Kl) for coalesced 16B S stores.
__global__ __launch_bounds__(256) void s_gemm(const unsigned short* __restrict__ qs,
                                              const unsigned short* __restrict__ ks,
                                              __half* __restrict__ S,
                                              float2* __restrict__ part) {
    __shared__ __align__(16) unsigned short smem[17408];  // Ql|Kl (32KB) aliased w/ Sl[128][136]
    __shared__ float2 sPart[4][128];
    unsigned short (*Ql)[64] = (unsigned short (*)[64])&smem[0];
    unsigned short (*Kl)[64] = (unsigned short (*)[64])&smem[8192];
    const int bid = blockIdx.x;
    const int b = bid >> 10;
    const int rem = bid & 1023;
    const int mt = rem >> 5;            // q tile index (0..31)
    const int m0 = mt << 7;
    const int n0 = (rem & 31) << 7;     // key tile (fastest -> k panel L2 reuse)
    const unsigned short* qb = qs + (size_t)b * Tn * Hn;
    const unsigned short* kb = ks + (size_t)b * Tn * Hn;
    const int t = threadIdx.x;
    const int lane = t & 63, wid = t >> 6;
    const int wr = (wid >> 1) * 64, wc = (wid & 1) * 64;
    const int fr = lane & 15, fq = lane >> 4;
    const int sr = lane >> 3, sc = lane & 7;
    f32x4 acc[4][4] = {};
    #pragma unroll
    for (int kh = 0; kh < 2; ++kh) {
        __syncthreads();
        #pragma unroll
        for (int s = 0; s < 4; ++s) {
            int seg = wid * 4 + s;
            int r = seg * 8 + sr;
            gload16(&qb[(size_t)(m0 + r) * Hn + kh * 64 + sc * 8],
                    (char*)&smem[0] + seg * 1024 + lane * 16);
            gload16(&kb[(size_t)(n0 + r) * Hn + kh * 64 + sc * 8],
                    (char*)&smem[0] + 16384 + seg * 1024 + lane * 16);
        }
        __syncthreads();
        #pragma unroll
        for (int ksub = 0; ksub < 2; ++ksub) {
            bf16x8 av[4], bv[4];
            #pragma unroll
            for (int mi = 0; mi < 4; ++mi)
                av[mi] = *reinterpret_cast<const bf16x8*>(&Ql[wr + mi * 16 + fr][ksub * 32 + fq * 8]);
            #pragma unroll
            for (int ni = 0; ni < 4; ++ni)
                bv[ni] = *reinterpret_cast<const bf16x8*>(&Kl[wc + ni * 16 + fr][ksub * 32 + fq * 8]);
            #pragma unroll
            for (int mi = 0; mi < 4; ++mi)
                #pragma unroll
                for (int ni = 0; ni < 4; ++ni)
                    acc[mi][ni] = __builtin_amdgcn_mfma_f32_16x16x32_bf16(av[mi], bv[ni], acc[mi][ni], 0, 0, 0);
        }
    }
    // fused per-column (over q) stats: in-lane 16 vals -> shfl over fq -> LDS over waves
    #pragma unroll
    for (int ni = 0; ni < 4; ++ni) {
        float mm = -INFINITY;
        #pragma unroll
        for (int mi = 0; mi < 4; ++mi)
            #pragma unroll
            for (int r = 0; r < 4; ++r)
                mm = fmaxf(mm, acc[mi][ni][r]);
        float ll = 0.f;
        #pragma unroll
        for (int mi = 0; mi < 4; ++mi)
            #pragma unroll
            for (int r = 0; r < 4; ++r)
                ll += __builtin_amdgcn_exp2f(acc[mi][ni][r] - mm);
        #pragma unroll
        for (int off = 16; off <= 32; off <<= 1) {
            float mo = __shfl_xor(mm, off);
            float lo = __shfl_xor(ll, off);
            float mn = fmaxf(mm, mo);
            ll = ll * __builtin_amdgcn_exp2f(mm - mn) + lo * __builtin_amdgcn_exp2f(mo - mn);
            mm = mn;
        }
        if (fq == 0) sPart[wid][wc + ni * 16 + fr] = make_float2(mm, ll);
    }
    __syncthreads();   // sPart ready AND all Ql/Kl reads complete (alias-safe)
    if (t < 128) {
        int col = t;
        int w = col >> 6;
        float2 a = sPart[w][col];
        float2 c2 = sPart[w + 2][col];
        float mn = fmaxf(a.x, c2.x);
        float L = a.y * __builtin_amdgcn_exp2f(a.x - mn) + c2.y * __builtin_amdgcn_exp2f(c2.x - mn);
        part[((size_t)b * Tn + n0 + col) * 32 + mt] = make_float2(mn, L);
    }
    // restage S tile into LDS for coalesced stores
    __half (*Sl)[136] = (__half (*)[136])&smem[0];
    #pragma unroll
    for (int mi = 0; mi < 4; ++mi)
        #pragma unroll
        for (int ni = 0; ni < 4; ++ni)
            #pragma unroll
            for (int r = 0; r < 4; ++r)
                Sl[wr + mi * 16 + fq * 4 + r][wc + ni * 16 + fr] = __float2half(acc[mi][ni][r]);
    __syncthreads();
    __half* Sb = S + (size_t)b * Tn * Tn;
    const int orow = t >> 1, oc = (t & 1) * 64;
    #pragma unroll
    for (int j = 0; j < 8; ++j)
        *reinterpret_cast<u32x4*>(&Sb[(size_t)(m0 + orow) * Tn + n0 + oc + j * 8]) =
            *reinterpret_cast<const u32x4*>(&Sl[orow][oc + j * 8]);
}

// ---------------- K3: combine partials -> mr[b][k] = m + log2(l) -------------
__global__ __launch_bounds__(256) void stats_comb(const float2* __restrict__ part,
                                                  float* __restrict__ stats) {
    int g = blockIdx.x * 256 + threadIdx.x;   // 8*4096
    const float2* pp = part + (size_t)g * 32;
    float M = -INFINITY;
    #pragma unroll
    for (int i = 0; i < 32; ++i) M = fmaxf(M, pp[i].x);
    float L = 0.f;
    #pragma unroll
    for (int i = 0; i < 32; ++i) L += pp[i].y * __builtin_amdgcn_exp2f(pp[i].x - M);
    stats[g] = M + __log2f(L);
}

// ---------------- K4: out = exp2(S'-mr) . V — P built in-register ------------
// BM=64, BN=128, BK=64; 4 waves. S(t+1)+V(t+1) prefetched before compute(t);
// one barrier/step. V gload source pre-swizzled (chunk ^= row&7).
__global__ __launch_bounds__(256) void pv_gemm(const __half* __restrict__ S,
                                               const float* __restrict__ mrs,
                                               const unsigned short* __restrict__ vT,
                                               float* __restrict__ out) {
    __shared__ __align__(16) unsigned short Vl[2][128][64];  // 32 KB dbuf
    const int bid = blockIdx.x;
    const int b = bid >> 6;
    const int q0 = (bid & 63) * 64;
    const int t = threadIdx.x;
    const int lane = t & 63, wid = t >> 6;
    const int wr = (wid & 1) * 32, wc = (wid >> 1) * 64;
    const int fr = lane & 15, fq = lane >> 4;
    const int sr = lane >> 3, sc = lane & 7;
    const __half* Sb = S + (size_t)b * Tn * Tn;
    const unsigned short* Vb = vT + (size_t)b * Hn * Tn;
    const float* mrb = mrs + (size_t)b * Tn;
    const __half* srow0 = Sb + (size_t)(q0 + wr + fr) * Tn;
    const __half* srow1 = Sb + (size_t)(q0 + wr + 16 + fr) * Tn;

    f32x4 acc[2][4] = {};
    u32x4 rc00, rc01, rc10, rc11;

    // prologue: V(0) gload + S(0) reg loads
    #pragma unroll
    for (int s = 0; s < 4; ++s) {
        int seg = wid * 4 + s;
        int r = seg * 8 + sr;
        int c = sc ^ (r & 7);
        gload16(&Vb[(size_t)r * Tn + c * 8], (char*)Vl + seg * 1024 + lane * 16);
    }
    rc00 = *reinterpret_cast<const u32x4*>(srow0 + fq * 8);
    rc01 = *reinterpret_cast<const u32x4*>(srow0 + 32 + fq * 8);
    rc10 = *reinterpret_cast<const u32x4*>(srow1 + fq * 8);
    rc11 = *reinterpret_cast<const u32x4*>(srow1 + 32 + fq * 8);
    __syncthreads();

    int cur = 0;
    for (int kt = 0; kt < 64; ++kt) {
        u32x4 rn00 = {}, rn01 = {}, rn10 = {}, rn11 = {};
        if (kt < 63) {
            const int kn = (kt + 1) * 64;
            #pragma unroll
            for (int s = 0; s < 4; ++s) {
                int seg = wid * 4 + s;
                int r = seg * 8 + sr;
                int c = sc ^ (r & 7);
                gload16(&Vb[(size_t)r * Tn + kn + c * 8],
                        (char*)Vl + (cur ^ 1) * 16384 + seg * 1024 + lane * 16);
            }
            rn00 = *reinterpret_cast<const u32x4*>(srow0 + kn + fq * 8);
            rn01 = *reinterpret_cast<const u32x4*>(srow0 + kn + 32 + fq * 8);
            rn10 = *reinterpret_cast<const u32x4*>(srow1 + kn + fq * 8);
            rn11 = *reinterpret_cast<const u32x4*>(srow1 + kn + 32 + fq * 8);
        }
        #pragma unroll
        for (int ksub = 0; ksub < 2; ++ksub) {
            const float* mp = mrb + kt * 64 + ksub * 32 + fq * 8;
            float4 ma = *reinterpret_cast<const float4*>(mp);
            float4 mb2 = *reinterpret_cast<const float4*>(mp + 4);
            float mk[8] = {ma.x, ma.y, ma.z, ma.w, mb2.x, mb2.y, mb2.z, mb2.w};
            bf16x8 av0 = expfrag(ksub ? rc01 : rc00, mk);
            bf16x8 av1 = expfrag(ksub ? rc11 : rc10, mk);
            #pragma unroll
            for (int ni = 0; ni < 4; ++ni) {
                int row = wc + ni * 16 + fr;
                int ch = (ksub * 4 + fq) ^ (row & 7);
                bf16x8 bv = *reinterpret_cast<const bf16x8*>(
                    (const char*)Vl + cur * 16384 + row * 128 + ch * 16);
                acc[0][ni] = __builtin_amdgcn_mfma_f32_16x16x32_bf16(av0, bv, acc[0][ni], 0, 0, 0);
                acc[1][ni] = __builtin_amdgcn_mfma_f32_16x16x32_bf16(av1, bv, acc[1][ni], 0, 0, 0);
            }
        }
        __syncthreads();
        cur ^= 1;
        rc00 = rn00; rc01 = rn01; rc10 = rn10; rc11 = rn11;
    }
    #pragma unroll
    for (int mi = 0; mi < 2; ++mi)
        #pragma unroll
        for (int ni = 0; ni < 4; ++ni)
            #pragma unroll
            for (int r = 0; r < 4; ++r) {
                int row = q0 + wr + mi * 16 + fq * 4 + r;
                int col = wc + ni * 16 + fr;
                out[((size_t)b * Tn + row) * Hn + col] = acc[mi][ni][r];
            }
}

extern "C" void kernel_launch(void* const* d_in, const int* in_sizes, int n_in,
                              void* d_out, int out_size, void* d_ws, size_t ws_size,
                              hipStream_t stream) {
    const float* x  = (const float*)d_in[0];
    const float* Wq = (const float*)d_in[1];
    const float* Wk = (const float*)d_in[2];
    const float* Wv = (const float*)d_in[3];
    float* out = (float*)d_out;

    char* p = (char*)d_ws;
    unsigned short* qs = (unsigned short*)p; p += (size_t)Bn * Tn * Hn * 2;
    unsigned short* ks = (unsigned short*)p; p += (size_t)Bn * Tn * Hn * 2;
    unsigned short* vT = (unsigned short*)p; p += (size_t)Bn * Tn * Hn * 2;
    unsigned short* Wt = (unsigned short*)p; p += (size_t)3 * En * Hn * 2;
    unsigned short* xb = (unsigned short*)p; p += (size_t)Bn * Tn * En * 2;
    __half* S          = (__half*)p;         p += (size_t)Bn * Tn * Tn * 2;
    float2* part       = (float2*)p;         p += (size_t)Bn * Tn * 32 * sizeof(float2);
    float* stats       = (float*)p;          p += (size_t)Bn * Tn * sizeof(float2);
    size_t needed = (size_t)(p - (char*)d_ws);
    if (ws_size < needed) return;  // workspace too small: leave output poisoned as a clear signal

    conv_x<<<dim3(Bn * Tn * En / (256 * 8)), dim3(256), 0, stream>>>(x, xb);
    prep_w<<<dim3(3 * En * Hn / 256), dim3(256), 0, stream>>>(Wq, Wk, Wv, Wt);
    qkv_mfma<<<dim3((Bn * Tn / 128) * 3), dim3(256), 0, stream>>>(xb, Wt, qs, ks, vT);
    s_gemm<<<dim3(Bn * (Tn / 128) * (Tn / 128)), dim3(256), 0, stream>>>(qs, ks, S, part);
    stats_comb<<<dim3(Bn * Tn / 256), dim3(256), 0, stream>>>(part, stats);
    pv_gemm<<<dim3(Bn * (Tn / 64)), dim3(256), 0, stream>>>(S, stats, vT, out);
}

// Round 7
// 294.967 us; speedup vs baseline: 1.5141x; 1.5141x over previous
//
#include <hip/hip_runtime.h>
#include <hip/hip_bf16.h>
#include <hip/hip_fp16.h>

#define Bn 8
#define Tn 4096
#define En 2048
#define Hn 128

typedef __attribute__((ext_vector_type(8))) short bf16x8;
typedef __attribute__((ext_vector_type(4))) float f32x4;
typedef __attribute__((ext_vector_type(4))) unsigned int u32x4;

typedef const __attribute__((address_space(1))) unsigned int* gptr_t;
typedef __attribute__((address_space(3))) unsigned int* lptr_t;

static __device__ __forceinline__ void gload16(const void* g, void* l) {
    __builtin_amdgcn_global_load_lds((gptr_t)g, (lptr_t)l, 16, 0, 0);
}

static __device__ __forceinline__ unsigned short f2bf(float f) {
    union { float f; unsigned u; } v; v.f = f;
    unsigned r = v.u + 0x7FFFu + ((v.u >> 16) & 1u);
    return (unsigned short)(r >> 16);
}

#define MFMA16(a, b, c) __builtin_amdgcn_mfma_f32_16x16x32_bf16((a), (b), (c), 0, 0, 0)
#define EXP2F(x) __builtin_amdgcn_exp2f(x)

// ---------------- K-1: x fp32 -> bf16, one streaming pass --------------------
__global__ __launch_bounds__(256) void conv_x(const float* __restrict__ x,
                                              unsigned short* __restrict__ xb) {
    size_t i = ((size_t)blockIdx.x * 256 + threadIdx.x) * 8;
    float4 a = *reinterpret_cast<const float4*>(x + i);
    float4 b = *reinterpret_cast<const float4*>(x + i + 4);
    ushort4 o0, o1;
    o0.x = f2bf(a.x); o0.y = f2bf(a.y); o0.z = f2bf(a.z); o0.w = f2bf(a.w);
    o1.x = f2bf(b.x); o1.y = f2bf(b.y); o1.z = f2bf(b.z); o1.w = f2bf(b.w);
    *reinterpret_cast<ushort4*>(xb + i) = o0;
    *reinterpret_cast<ushort4*>(xb + i + 4) = o1;
}

// ---------------- K0: transpose+convert weights, fold SCALE*log2e into Wq ----
__global__ __launch_bounds__(256) void prep_w(const float* __restrict__ Wq,
                                              const float* __restrict__ Wk,
                                              const float* __restrict__ Wv,
                                              unsigned short* __restrict__ Wt) {
    int idx = blockIdx.x * 256 + threadIdx.x;
    int w = idx / (En * Hn);
    int rem = idx - w * (En * Hn);
    int kx = rem >> 7;
    int n  = rem & 127;
    const float* W = (w == 0) ? Wq : (w == 1) ? Wk : Wv;
    float f = W[rem];
    if (w == 0) f *= (0.17677669529663687f * 1.4426950408889634f); // 32^-0.5 * log2(e)
    Wt[(size_t)w * En * Hn + (size_t)n * En + kx] = f2bf(f);
}

// ---------------- K1: qkv projection — m97 structure, pure bf16 --------------
__global__ __launch_bounds__(256, 3) void qkv_mfma(const unsigned short* __restrict__ xb,
                                                   const unsigned short* __restrict__ Wt,
                                                   unsigned short* __restrict__ qs,
                                                   unsigned short* __restrict__ ks,
                                                   unsigned short* __restrict__ vT) {
    __shared__ unsigned short Al[128][64];
    __shared__ unsigned short Bl[128][64];
    const int bid = blockIdx.x;
    const int w = bid % 3;
    const int m0 = (bid / 3) * 128;
    const int b = m0 >> 12;
    const int tb = m0 & (Tn - 1);
    const int t = threadIdx.x;
    const int lane = t & 63, wid = t >> 6;
    const int wr = (wid >> 1) * 64, wc = (wid & 1) * 64;
    const int fr = lane & 15, fq = lane >> 4;
    const unsigned short* Wb = Wt + (size_t)w * En * Hn;
    const int sr = lane >> 3, sc = lane & 7;

    f32x4 acc[4][4] = {};
    for (int k0 = 0; k0 < En; k0 += 64) {
        __syncthreads();
        #pragma unroll
        for (int s = 0; s < 4; ++s) {
            int seg = wid * 4 + s;
            int r = seg * 8 + sr;
            gload16(&xb[(size_t)(m0 + r) * En + k0 + sc * 8],
                    (char*)&Al[0][0] + seg * 1024 + lane * 16);
            gload16(&Wb[(size_t)r * En + k0 + sc * 8],
                    (char*)&Bl[0][0] + seg * 1024 + lane * 16);
        }
        __syncthreads();
        #pragma unroll
        for (int ksub = 0; ksub < 2; ++ksub) {
            bf16x8 av[4], bv[4];
            #pragma unroll
            for (int mi = 0; mi < 4; ++mi)
                av[mi] = *reinterpret_cast<const bf16x8*>(&Al[wr + mi * 16 + fr][ksub * 32 + fq * 8]);
            #pragma unroll
            for (int ni = 0; ni < 4; ++ni)
                bv[ni] = *reinterpret_cast<const bf16x8*>(&Bl[wc + ni * 16 + fr][ksub * 32 + fq * 8]);
            #pragma unroll
            for (int mi = 0; mi < 4; ++mi)
                #pragma unroll
                for (int ni = 0; ni < 4; ++ni)
                    acc[mi][ni] = MFMA16(av[mi], bv[ni], acc[mi][ni]);
        }
    }

    if (w < 2) {
        unsigned short* out = (w == 0) ? qs : ks;
        #pragma unroll
        for (int mi = 0; mi < 4; ++mi)
            #pragma unroll
            for (int ni = 0; ni < 4; ++ni)
                #pragma unroll
                for (int r = 0; r < 4; ++r) {
                    int row = m0 + wr + mi * 16 + fq * 4 + r;
                    int col = wc + ni * 16 + fr;
                    out[(size_t)row * Hn + col] = f2bf(acc[mi][ni][r]);
                }
    } else {
        #pragma unroll
        for (int mi = 0; mi < 4; ++mi)
            #pragma unroll
            for (int ni = 0; ni < 4; ++ni)
                #pragma unroll
                for (int r = 0; r < 4; ++r) {
                    int tt = tb + wr + mi * 16 + fq * 4 + r;
                    int h  = wc + ni * 16 + fr;
                    vT[((size_t)b * Hn + h) * Tn + tt] = f2bf(acc[mi][ni][r]);
                }
    }
}

// ---------------- K2: column stats via recomputed S^T (no S materialized) ----
// S^T = mfma(K, Q): acc[k-row][q-col]; softmax axis = q -> reduce over cols.
// Block = (b, kt:64 keys, qh:half of q). K-tile stationary in registers.
__global__ __launch_bounds__(256, 4) void stats_qk(const unsigned short* __restrict__ qs,
                                                   const unsigned short* __restrict__ ks,
                                                   float2* __restrict__ part) {
    __shared__ __align__(16) unsigned short Kl[64][128];
    __shared__ __align__(16) unsigned short Ql[64][128];
    const int bid = blockIdx.x;              // 8 * 64 * 2 = 1024
    const int b = bid >> 7;
    const int kt = (bid >> 1) & 63;
    const int qh = bid & 1;
    const int k0 = kt * 64;
    const unsigned short* qb = qs + (size_t)b * Tn * Hn;
    const unsigned short* kb = ks + (size_t)b * Tn * Hn;
    const int t = threadIdx.x;
    const int lane = t & 63, wid = t >> 6;
    const int wk = wid >> 1, wq = wid & 1;
    const int fr = lane & 15, fq = lane >> 4;
    const int srow = t >> 4, schk = t & 15;

    // stage K tile once (source pre-swizzled: chunk ^= row&15)
    #pragma unroll
    for (int it = 0; it < 4; ++it) {
        int r = it * 16 + srow;
        gload16(&kb[(size_t)(k0 + r) * Hn + ((schk ^ (r & 15)) * 8)],
                (char*)&Kl[0][0] + it * 4096 + t * 16);
    }
    __syncthreads();
    // hoist stationary A-frags (K)
    bf16x8 av[2][4];
    #pragma unroll
    for (int mi = 0; mi < 2; ++mi)
        #pragma unroll
        for (int kc = 0; kc < 4; ++kc) {
            int row = wk * 32 + mi * 16 + fr;
            int ch = (kc * 4 + fq) ^ (row & 15);
            av[mi][kc] = *reinterpret_cast<const bf16x8*>((const char*)Kl + row * 256 + ch * 16);
        }

    float m[2][4], l[2][4];
    #pragma unroll
    for (int mi = 0; mi < 2; ++mi)
        #pragma unroll
        for (int r = 0; r < 4; ++r) { m[mi][r] = -INFINITY; l[mi][r] = 0.f; }

    for (int step = 0; step < 32; ++step) {
        const int q0 = qh * 2048 + step * 64;
        #pragma unroll
        for (int it = 0; it < 4; ++it) {
            int r = it * 16 + srow;
            gload16(&qb[(size_t)(q0 + r) * Hn + ((schk ^ (r & 15)) * 8)],
                    (char*)&Ql[0][0] + it * 4096 + t * 16);
        }
        __syncthreads();
        f32x4 acc[2][2] = {};
        #pragma unroll
        for (int kc = 0; kc < 4; ++kc) {
            bf16x8 bv[2];
            #pragma unroll
            for (int ni = 0; ni < 2; ++ni) {
                int row = wq * 32 + ni * 16 + fr;
                int ch = (kc * 4 + fq) ^ (row & 15);
                bv[ni] = *reinterpret_cast<const bf16x8*>((const char*)Ql + row * 256 + ch * 16);
            }
            #pragma unroll
            for (int mi = 0; mi < 2; ++mi)
                #pragma unroll
                for (int ni = 0; ni < 2; ++ni)
                    acc[mi][ni] = MFMA16(av[mi][kc], bv[ni], acc[mi][ni]);
        }
        #pragma unroll
        for (int mi = 0; mi < 2; ++mi)
            #pragma unroll
            for (int r = 0; r < 4; ++r) {
                float v0 = acc[mi][0][r], v1 = acc[mi][1][r];
                float mn = fmaxf(m[mi][r], fmaxf(v0, v1));
                l[mi][r] = l[mi][r] * EXP2F(m[mi][r] - mn) + EXP2F(v0 - mn) + EXP2F(v1 - mn);
                m[mi][r] = mn;
            }
        __syncthreads();   // protect Ql before next stage
    }
    // reduce over fr (q direction) within 16-lane groups
    #pragma unroll
    for (int off = 1; off <= 8; off <<= 1) {
        #pragma unroll
        for (int mi = 0; mi < 2; ++mi)
            #pragma unroll
            for (int r = 0; r < 4; ++r) {
                float mo = __shfl_xor(m[mi][r], off);
                float lo = __shfl_xor(l[mi][r], off);
                float mn = fmaxf(m[mi][r], mo);
                l[mi][r] = l[mi][r] * EXP2F(m[mi][r] - mn) + lo * EXP2F(mo - mn);
                m[mi][r] = mn;
            }
    }
    if (fr == 0) {
        #pragma unroll
        for (int mi = 0; mi < 2; ++mi)
            #pragma unroll
            for (int r = 0; r < 4; ++r) {
                int k = k0 + wk * 32 + mi * 16 + fq * 4 + r;
                part[((size_t)b * Tn + k) * 4 + qh * 2 + wq] = make_float2(m[mi][r], l[mi][r]);
            }
    }
}

// ---------------- K3: combine 4 partials -> mr[b][k] = m + log2(l) -----------
__global__ __launch_bounds__(256) void stats_comb(const float2* __restrict__ part,
                                                  float* __restrict__ mr) {
    int g = blockIdx.x * 256 + threadIdx.x;   // 8*4096
    const float2* pp = part + (size_t)g * 4;
    float2 p0 = pp[0], p1 = pp[1], p2 = pp[2], p3 = pp[3];
    float M = fmaxf(fmaxf(p0.x, p1.x), fmaxf(p2.x, p3.x));
    float L = p0.y * EXP2F(p0.x - M) + p1.y * EXP2F(p1.x - M) +
              p2.y * EXP2F(p2.x - M) + p3.y * EXP2F(p3.x - M);
    mr[g] = M + __log2f(L);
}

// ---------------- K4: fused attn: recompute S^T, P^T in LDS, PV --------------
// Block = (b, q-tile of 64). S^T = mfma(K,Q) -> b64-packed P^T writes;
// out^T = mfma(V^T, P^T). Vl double-buffered; 2 barriers/step.
__global__ __launch_bounds__(256, 2) void attn_pv(const unsigned short* __restrict__ qs,
                                                  const unsigned short* __restrict__ ks,
                                                  const unsigned short* __restrict__ vT,
                                                  const float* __restrict__ mr,
                                                  float* __restrict__ out) {
    // byte layout: Q 0..16384 | K 16384..32768 | V dbuf 32768..65536 | P 65536..73728
    __shared__ __align__(16) char smem[73728];
    char* Qb = smem;
    char* Kb = smem + 16384;
    char* Vb2 = smem + 32768;
    char* Pb = smem + 65536;
    const int bid = blockIdx.x;           // 8 * 64 = 512
    const int b = bid >> 6;
    const int q0 = (bid & 63) * 64;
    const unsigned short* qg = qs + (size_t)b * Tn * Hn;
    const unsigned short* kg = ks + (size_t)b * Tn * Hn;
    const unsigned short* vg = vT + (size_t)b * Hn * Tn;
    const float* mrb = mr + (size_t)b * Tn;
    const int t = threadIdx.x;
    const int lane = t & 63, wid = t >> 6;
    const int wk = wid >> 1, wq = wid & 1;   // S-phase: k-half / q-half; PV: h-half / q-half
    const int fr = lane & 15, fq = lane >> 4;
    const int srow16 = t >> 4, schk16 = t & 15;  // 128-col tiles (K, Q)
    const int srow8 = t >> 3, schk8 = t & 7;     // 64-col tiles (V)

    // prologue: stage Q (persistent), K(0), V[0](0)
    #pragma unroll
    for (int it = 0; it < 4; ++it) {
        int r = it * 16 + srow16;
        gload16(&qg[(size_t)(q0 + r) * Hn + ((schk16 ^ (r & 15)) * 8)], Qb + it * 4096 + t * 16);
        gload16(&kg[(size_t)r * Hn + ((schk16 ^ (r & 15)) * 8)], Kb + it * 4096 + t * 16);
        int rv = it * 32 + srow8;
        gload16(&vg[(size_t)rv * Tn + ((schk8 ^ (rv & 7)) * 8)], Vb2 + it * 4096 + t * 16);
    }
    __syncthreads();
    // hoist stationary B-frags (Q)
    bf16x8 bq[2][4];
    #pragma unroll
    for (int ni = 0; ni < 2; ++ni)
        #pragma unroll
        for (int kc = 0; kc < 4; ++kc) {
            int row = wq * 32 + ni * 16 + fr;
            int ch = (kc * 4 + fq) ^ (row & 15);
            bq[ni][kc] = *reinterpret_cast<const bf16x8*>(Qb + row * 256 + ch * 16);
        }

    f32x4 acc_o[4][2] = {};
    for (int kt = 0; kt < 64; ++kt) {
        const int k0 = kt * 64;
        // ---- phase A: S^T for this k-tile, P^T -> LDS ----
        f32x4 acc_s[2][2] = {};
        #pragma unroll
        for (int kc = 0; kc < 4; ++kc) {
            bf16x8 avk[2];
            #pragma unroll
            for (int mi = 0; mi < 2; ++mi) {
                int row = wk * 32 + mi * 16 + fr;
                int ch = (kc * 4 + fq) ^ (row & 15);
                avk[mi] = *reinterpret_cast<const bf16x8*>(Kb + row * 256 + ch * 16);
            }
            #pragma unroll
            for (int mi = 0; mi < 2; ++mi)
                #pragma unroll
                for (int ni = 0; ni < 2; ++ni)
                    acc_s[mi][ni] = MFMA16(avk[mi], bq[ni][kc], acc_s[mi][ni]);
        }
        #pragma unroll
        for (int mi = 0; mi < 2; ++mi) {
            float4 mk = *reinterpret_cast<const float4*>(&mrb[k0 + wk * 32 + mi * 16 + fq * 4]);
            #pragma unroll
            for (int ni = 0; ni < 2; ++ni) {
                unsigned p01 = (unsigned)f2bf(EXP2F(acc_s[mi][ni][0] - mk.x)) |
                               ((unsigned)f2bf(EXP2F(acc_s[mi][ni][1] - mk.y)) << 16);
                unsigned p23 = (unsigned)f2bf(EXP2F(acc_s[mi][ni][2] - mk.z)) |
                               ((unsigned)f2bf(EXP2F(acc_s[mi][ni][3] - mk.w)) << 16);
                int q = wq * 32 + ni * 16 + fr;
                int chunk = (wk * 4 + mi * 2 + (fq >> 1)) ^ (q & 7);
                *reinterpret_cast<uint2*>(Pb + q * 128 + chunk * 16 + (fq & 1) * 8) =
                    make_uint2(p01, p23);
            }
        }
        __syncthreads();   // barrier 1: P ready, K reads done
        // ---- phase B: prefetch next K/V; PV MFMAs ----
        if (kt < 63) {
            const int kn = k0 + 64;
            #pragma unroll
            for (int it = 0; it < 4; ++it) {
                int r = it * 16 + srow16;
                gload16(&kg[(size_t)(kn + r) * Hn + ((schk16 ^ (r & 15)) * 8)],
                        Kb + it * 4096 + t * 16);
                int rv = it * 32 + srow8;
                gload16(&vg[(size_t)rv * Tn + kn + ((schk8 ^ (rv & 7)) * 8)],
                        Vb2 + ((kt + 1) & 1) * 16384 + it * 4096 + t * 16);
            }
        }
        const char* Vcur = Vb2 + (kt & 1) * 16384;
        #pragma unroll
        for (int kc = 0; kc < 2; ++kc) {
            bf16x8 bp[2];
            #pragma unroll
            for (int ni = 0; ni < 2; ++ni) {
                int qrow = wq * 32 + ni * 16 + fr;
                int ch = (kc * 4 + fq) ^ (qrow & 7);
                bp[ni] = *reinterpret_cast<const bf16x8*>(Pb + qrow * 128 + ch * 16);
            }
            #pragma unroll
            for (int mi = 0; mi < 4; ++mi) {
                int row = wk * 64 + mi * 16 + fr;
                int ch = (kc * 4 + fq) ^ (row & 7);
                bf16x8 avv = *reinterpret_cast<const bf16x8*>(Vcur + row * 128 + ch * 16);
                #pragma unroll
                for (int ni = 0; ni < 2; ++ni)
                    acc_o[mi][ni] = MFMA16(avv, bp[ni], acc_o[mi][ni]);
            }
        }
        __syncthreads();   // barrier 2: gloads drained; P/V reads done
    }

    // epilogue: out^T acc -> Ol[q][h] in LDS (aliases Q/K/V0), coalesced stores
    float* Ol = (float*)smem;   // [64][132]
    #pragma unroll
    for (int mi = 0; mi < 4; ++mi)
        #pragma unroll
        for (int ni = 0; ni < 2; ++ni) {
            int q = wq * 32 + ni * 16 + fr;
            int h = wk * 64 + mi * 16 + fq * 4;
            *reinterpret_cast<float4*>(&Ol[q * 132 + h]) =
                make_float4(acc_o[mi][ni][0], acc_o[mi][ni][1], acc_o[mi][ni][2], acc_o[mi][ni][3]);
        }
    __syncthreads();
    #pragma unroll
    for (int j = 0; j < 8; ++j) {
        int idx = j * 256 + t;
        int row = idx >> 5, c = (idx & 31) * 4;
        *reinterpret_cast<float4*>(&out[((size_t)b * Tn + q0 + row) * Hn + c]) =
            *reinterpret_cast<const float4*>(&Ol[row * 132 + c]);
    }
}

extern "C" void kernel_launch(void* const* d_in, const int* in_sizes, int n_in,
                              void* d_out, int out_size, void* d_ws, size_t ws_size,
                              hipStream_t stream) {
    const float* x  = (const float*)d_in[0];
    const float* Wq = (const float*)d_in[1];
    const float* Wk = (const float*)d_in[2];
    const float* Wv = (const float*)d_in[3];
    float* out = (float*)d_out;

    char* p = (char*)d_ws;
    unsigned short* qs = (unsigned short*)p; p += (size_t)Bn * Tn * Hn * 2;
    unsigned short* ks = (unsigned short*)p; p += (size_t)Bn * Tn * Hn * 2;
    unsigned short* vT = (unsigned short*)p; p += (size_t)Bn * Tn * Hn * 2;
    unsigned short* Wt = (unsigned short*)p; p += (size_t)3 * En * Hn * 2;
    unsigned short* xb = (unsigned short*)p; p += (size_t)Bn * Tn * En * 2;
    float2* part       = (float2*)p;         p += (size_t)Bn * Tn * 4 * sizeof(float2);
    float* mr          = (float*)p;          p += (size_t)Bn * Tn * sizeof(float);
    size_t needed = (size_t)(p - (char*)d_ws);
    if (ws_size < needed) return;

    conv_x<<<dim3(Bn * Tn * En / (256 * 8)), dim3(256), 0, stream>>>(x, xb);
    prep_w<<<dim3(3 * En * Hn / 256), dim3(256), 0, stream>>>(Wq, Wk, Wv, Wt);
    qkv_mfma<<<dim3((Bn * Tn / 128) * 3), dim3(256), 0, stream>>>(xb, Wt, qs, ks, vT);
    stats_qk<<<dim3(Bn * 64 * 2), dim3(256), 0, stream>>>(qs, ks, part);
    stats_comb<<<dim3(Bn * Tn / 256), dim3(256), 0, stream>>>(part, mr);
    attn_pv<<<dim3(Bn * 64), dim3(256), 0, stream>>>(qs, ks, vT, mr, out);
}